// Round 8
// baseline (195.184 us; speedup 1.0000x reference)
//
#include <hip/hip_runtime.h>
#include <stdint.h>

typedef unsigned short u16;
typedef __attribute__((ext_vector_type(8))) __bf16 bf16x8;
typedef __attribute__((ext_vector_type(8))) short short8;
typedef __attribute__((ext_vector_type(4))) float f32x4;
typedef __attribute__((ext_vector_type(16))) float f32x16;
typedef __attribute__((ext_vector_type(4))) uint32_t u32x4;

#define AS1 __attribute__((address_space(1)))
#define AS3 __attribute__((address_space(3)))

__device__ __forceinline__ void load_lds16(const void* g, void* l) {
    __builtin_amdgcn_global_load_lds((AS1 void*)g, (AS3 void*)l, 16, 0, 0);
}

__device__ __forceinline__ u16 f2bf(float f) {
    uint32_t u = __builtin_bit_cast(uint32_t, f);
    u += 0x7FFFu + ((u >> 16) & 1u);
    return (u16)(u >> 16);
}
__device__ __forceinline__ float bf2f(u16 v) {
    return __builtin_bit_cast(float, ((uint32_t)v) << 16);
}

__device__ __forceinline__ f32x4 mfma16(bf16x8 a, bf16x8 b, f32x4 c) {
    return __builtin_amdgcn_mfma_f32_16x16x32_bf16(a, b, c, 0, 0, 0);
}
__device__ __forceinline__ f32x16 mfma32(bf16x8 a, bf16x8 b, f32x16 c) {
    return __builtin_amdgcn_mfma_f32_32x32x16_bf16(a, b, c, 0, 0, 0);
}

// balanced max over an f32x16, nested fmax triples (max3-fusable, depth 4).
__device__ __forceinline__ float max16(const f32x16& s) {
    const float a0 = fmaxf(fmaxf(s[0], s[1]), s[2]);
    const float a1 = fmaxf(fmaxf(s[3], s[4]), s[5]);
    const float a2 = fmaxf(fmaxf(s[6], s[7]), s[8]);
    const float a3 = fmaxf(fmaxf(s[9], s[10]), s[11]);
    const float a4 = fmaxf(fmaxf(s[12], s[13]), s[14]);
    const float b0 = fmaxf(fmaxf(a0, a1), a2);
    const float b1 = fmaxf(fmaxf(a3, a4), s[15]);
    return fmaxf(b0, b1);
}

__device__ __forceinline__ float rcpf(float x) {
    float r;
    asm("v_rcp_f32 %0, %1" : "=v"(r) : "v"(x));
    return r;
}

// ---------------------------------------------------------------- fused cast f32->bf16
__global__ __launch_bounds__(256) void cast_all(const float* __restrict__ x,
                                                const float* __restrict__ wq,
                                                const float* __restrict__ wk,
                                                const float* __restrict__ wv,
                                                const float* __restrict__ wp,
                                                u16* __restrict__ xb,
                                                u16* __restrict__ wqkv,
                                                u16* __restrict__ wpb) {
    const int bid = blockIdx.x;
    const float* src;
    u16* dst;
    int boff;
    if (bid < 8192)       { src = x;  dst = xb;             boff = bid; }
    else if (bid < 9216)  { src = wq; dst = wqkv;           boff = bid - 8192; }
    else if (bid < 10240) { src = wk; dst = wqkv + 1048576; boff = bid - 9216; }
    else if (bid < 11264) { src = wv; dst = wqkv + 2097152; boff = bid - 10240; }
    else                  { src = wp; dst = wpb;            boff = bid - 11264; }
    const int i = (boff * 256 + threadIdx.x) * 4;
    const float4 v = *(const float4*)(src + i);
    u16 o0 = f2bf(v.x), o1 = f2bf(v.y), o2 = f2bf(v.z), o3 = f2bf(v.w);
    uint32_t lo = (uint32_t)o0 | ((uint32_t)o1 << 16);
    uint32_t hi = (uint32_t)o2 | ((uint32_t)o3 << 16);
    uint2 p; p.x = lo; p.y = hi;
    *(uint2*)(dst + i) = p;
}

// ---------------------------------------------------------------- 128x128 GEMM core
template<int KDIM>
__device__ __forceinline__ void gemm_core(const u16* __restrict__ A, const u16* __restrict__ Bw,
                                          int m0, int n0, char* lds, f32x4 acc[4][4]) {
    const int tid = threadIdx.x;
    const int w = tid >> 6, l = tid & 63;
    const int lg = l >> 4, lc = l & 15;
    const int wm = (w >> 1) * 64, wn = (w & 1) * 64;
    char* As = lds;
    char* Bs = lds + 16384;
    for (int kt = 0; kt < KDIM; kt += 64) {
#pragma unroll
        for (int i = 0; i < 4; ++i) {
            const int e = i * 256 + tid;
            const int row = e >> 3, c = e & 7;
            const int cs = c ^ (row & 7);
            load_lds16(A + (size_t)(m0 + row) * KDIM + kt + cs * 8, As + i * 4096 + w * 1024);
            load_lds16(Bw + (size_t)(n0 + row) * KDIM + kt + cs * 8, Bs + i * 4096 + w * 1024);
        }
        __syncthreads();
#pragma unroll
        for (int kk = 0; kk < 2; ++kk) {
            bf16x8 af[4], bfr[4];
            const int byo = kk * 64 + lg * 16;
#pragma unroll
            for (int mi = 0; mi < 4; ++mi) {
                const int row = wm + mi * 16 + lc;
                af[mi] = *(const bf16x8*)(As + row * 128 + (byo ^ ((row & 7) << 4)));
            }
#pragma unroll
            for (int ni = 0; ni < 4; ++ni) {
                const int row = wn + ni * 16 + lc;
                bfr[ni] = *(const bf16x8*)(Bs + row * 128 + (byo ^ ((row & 7) << 4)));
            }
#pragma unroll
            for (int mi = 0; mi < 4; ++mi)
#pragma unroll
                for (int ni = 0; ni < 4; ++ni)
                    acc[mi][ni] = mfma16(af[mi], bfr[ni], acc[mi][ni]);
        }
        __syncthreads();
    }
}

// ---------------------------------------------------------------- fused QKV projection
__global__ __launch_bounds__(256) void qkv_gemm(const u16* __restrict__ xb, const u16* __restrict__ wqkv,
                                                const float* __restrict__ bq, const float* __restrict__ bk,
                                                const float* __restrict__ bv,
                                                u16* __restrict__ qo, u16* __restrict__ ko, u16* __restrict__ vt) {
    __shared__ char lds[32768];
    f32x4 acc[4][4] = {};
    const int id = blockIdx.x;
    const int xcd = id & 7, sl = id >> 3;
    const int nIdx = sl >> 3, mloc = sl & 7;
    const int m0 = (xcd * 8 + mloc) * 128;
    const int n0 = nIdx * 128;
    gemm_core<1024>(xb, wqkv, m0, n0, lds, acc);
    const int which = n0 >> 10;
    const float* bias = which == 0 ? bq : (which == 1 ? bk : bv);
    const int tid = threadIdx.x;
    const int w = tid >> 6, l = tid & 63;
    const int lg = l >> 4, lc = l & 15;
    const int wm = (w >> 1) * 64, wn = (w & 1) * 64;
    if (which == 2) {
#pragma unroll
        for (int mi = 0; mi < 4; ++mi)
#pragma unroll
            for (int ni = 0; ni < 4; ++ni) {
                const int ng = n0 + wn + ni * 16 + lc;
                const int c = ng & 1023;
                const int h = c >> 6, d = c & 63;
                const float bb = bias[c];
                const int t0 = m0 + wm + mi * 16 + lg * 4;
                const int b = t0 >> 11, t = t0 & 2047;
                uint32_t w0 = (uint32_t)f2bf(acc[mi][ni][0] + bb) | ((uint32_t)f2bf(acc[mi][ni][1] + bb) << 16);
                uint32_t w1 = (uint32_t)f2bf(acc[mi][ni][2] + bb) | ((uint32_t)f2bf(acc[mi][ni][3] + bb) << 16);
                uint2 pk; pk.x = w0; pk.y = w1;
                *(uint2*)(vt + (((size_t)(b * 16 + h)) * 64 + d) * 2048 + t) = pk;
            }
    } else {
        u16* outb = which == 0 ? qo : ko;
#pragma unroll
        for (int mi = 0; mi < 4; ++mi)
#pragma unroll
            for (int ni = 0; ni < 4; ++ni)
#pragma unroll
                for (int r = 0; r < 4; ++r) {
                    const int m = m0 + wm + mi * 16 + lg * 4 + r;
                    const int ng = n0 + wn + ni * 16 + lc;
                    const int c = ng & 1023;
                    const float v = acc[mi][ni][r] + bias[c];
                    const int h = c >> 6, d = c & 63;
                    const int b = m >> 11, t = m & 2047;
                    outb[(((size_t)(b * 16 + h)) * 2048 + t) * 64 + d] = f2bf(v);
                }
    }
}

// ---------------------------------------------------------------- flash attention (causal)
// r8: SPLIT-KV duration flattening. Strips 0..7 (<=16 tile-rounds) run the
// UNCHANGED r6/r7 path writing attb directly. Strips 8..15 are split into two
// KV-half blocks (tiles [0,s+1) / [s+1,2s+2)), each writing a partial
// (O/l bf16, per-row m,l fp32) into workspace; attn_merge combines pairs.
// Max block duration: 32 -> 16 rounds (the r7 tail was strip-15 grinding 32
// serial rounds at 4 waves/CU; occupancy avg 25%).
// Per-XCD dispatch: id=xcd+8*slot, slot=hl*24+ty; 24 types LPT-ordered
// (longest first) per head; same-head grouping preserved for KV L2 locality.
// Type tables bit-packed (rule #20: no runtime-indexed local arrays).
#define CLOG 0.18033688f   /* 0.125 * log2(e) */
#define KINDBITS 0x0000009926499264ULL  /* 2b/type: 0=unsplit 1=splitA 2=splitB */
#define SLO 0x4AABB5CCDD6EEFF7ULL       /* 4b strip idx, types 0..15 */
#define SHI 0x01238899ULL               /* 4b strip idx, types 16..23 */

__global__ __launch_bounds__(256) __attribute__((amdgpu_waves_per_eu(4, 8)))
void attn_kernel(const u16* __restrict__ qbuf, const u16* __restrict__ kbuf,
                 const u16* __restrict__ vtb, u16* __restrict__ attb,
                 u16* __restrict__ pO, float2* __restrict__ pml) {
    __shared__ char lds[32768];  // [parity][ K 8KB | Vt 8KB ]
    const int tid = threadIdx.x;
    const int w = tid >> 6, l = tid & 63;
    const int l31 = l & 31, hi = l >> 5;
    const int id = blockIdx.x;
    const int xcd = id & 7, slot = id >> 3;
    const int hl = slot / 24;                  // head-local 0..7
    const int ty = slot - hl * 24;             // type 0..23
    const int kind = (int)((KINDBITS >> (2 * ty)) & 3ULL);
    const int s = (int)(((ty < 16) ? (SLO >> (4 * ty)) : (SHI >> (4 * (ty - 16)))) & 15ULL);
    const int bh = xcd * 8 + hl;
    const size_t base = (size_t)bh * 2048 * 64;
    const int qw0 = s * 128 + w * 32;          // this wave's 32 q rows
    const int jmax = (qw0 + 31) >> 6;
    const int j0 = (kind == 2) ? (s + 1) : 0;
    const int j1 = (kind == 1) ? (s + 1) : (2 * s + 2);
    const int qg = qw0 + l31;

    // Q B-fragments: lane holds q=qw0+l31, d=16t+8hi+j
    bf16x8 aqf[4];
#pragma unroll
    for (int t = 0; t < 4; ++t)
        aqf[t] = *(const bf16x8*)(qbuf + base + (size_t)(qw0 + l31) * 64 + t * 16 + hi * 8);

    f32x16 oacc[2];
#pragma unroll
    for (int i = 0; i < 16; ++i) { oacc[0][i] = 0.f; oacc[1][i] = 0.f; }
    float mrun = -3.0e38f, lrun = 0.f;   // lrun = OWN-HALF sums (cross-half deferred)

#define ISSUE_K(J, BUF)                                                                          \
    {                                                                                            \
        _Pragma("unroll")                                                                        \
        for (int i = 0; i < 2; ++i) {                                                            \
            const int e = i * 256 + tid;                                                         \
            const int row = e >> 3, c = e & 7;                                                   \
            const int cs = c ^ (row & 7);                                                        \
            load_lds16(kbuf + base + (size_t)((J) * 64 + row) * 64 + cs * 8,                     \
                       (BUF) + i * 4096 + w * 1024);                                             \
        }                                                                                        \
    }
#define ISSUE_VT(J, BUF)                                                                         \
    {                                                                                            \
        _Pragma("unroll")                                                                        \
        for (int i = 0; i < 2; ++i) {                                                            \
            const int e = i * 256 + tid;                                                         \
            const int row = e >> 3, c = e & 7;                                                   \
            const int cs = c ^ (row & 7);                                                        \
            load_lds16(vtb + base + (size_t)row * 2048 + (J) * 64 + cs * 8,                      \
                       (BUF) + i * 4096 + w * 1024);                                             \
        }                                                                                        \
    }

#define PVSTEP(W, KL, KS)                                                       \
    {                                                                           \
        const uint32_t wa = W[4 * (KL) + 0], wb_ = W[4 * (KL) + 1];             \
        const uint32_t wc = W[4 * (KL) + 2], wd = W[4 * (KL) + 3];              \
        const uint32_t xa = (uint32_t)__shfl_xor((int)wa, 32, 64);              \
        const uint32_t xb = (uint32_t)__shfl_xor((int)wb_, 32, 64);             \
        const uint32_t xc = (uint32_t)__shfl_xor((int)wc, 32, 64);              \
        const uint32_t xd = (uint32_t)__shfl_xor((int)wd, 32, 64);              \
        u32x4 pw;                                                               \
        pw[0] = hi ? xc : wa;                                                   \
        pw[1] = hi ? xd : wb_;                                                  \
        pw[2] = hi ? wc : xa;                                                   \
        pw[3] = hi ? wd : xb;                                                   \
        const bf16x8 paf = __builtin_bit_cast(bf16x8, pw);                      \
        __builtin_amdgcn_s_setprio(1);                                          \
        _Pragma("unroll")                                                       \
        for (int nb = 0; nb < 2; ++nb) {                                        \
            const int vrow = nb * 32 + l31;                                     \
            const bf16x8 bvf = *(const bf16x8*)(Vt + vrow * 128 +               \
                (((KS) * 32 + hi * 16) ^ ((vrow & 7) << 4)));                   \
            oacc[nb] = mfma32(paf, bvf, oacc[nb]);                              \
        }                                                                       \
        __builtin_amdgcn_s_setprio(0);                                          \
    }

#define SOFTMAX_PACK(SF, WV)                                                    \
    {                                                                           \
        float ps[8];                                                            \
        _Pragma("unroll")                                                       \
        for (int i = 0; i < 8; ++i) {                                           \
            const float p0 = exp2f(fmaf((SF)[2 * i], CLOG, -mrun));             \
            const float p1 = exp2f(fmaf((SF)[2 * i + 1], CLOG, -mrun));         \
            (SF)[2 * i] = p0;                                                   \
            (SF)[2 * i + 1] = p1;                                               \
            ps[i] = p0 + p1;                                                    \
        }                                                                       \
        lrun += ((ps[0] + ps[1]) + (ps[2] + ps[3])) +                           \
                ((ps[4] + ps[5]) + (ps[6] + ps[7]));                            \
        _Pragma("unroll")                                                       \
        for (int i = 0; i < 8; ++i) {                                           \
            uint32_t ww;                                                        \
            asm("v_cvt_pk_bf16_f32 %0, %1, %2"                                  \
                : "=v"(ww) : "v"((SF)[2 * i]), "v"((SF)[2 * i + 1]));           \
            (WV)[i] = ww;                                                       \
        }                                                                       \
    }

    {
        char* b0 = lds + (j0 & 1) * 16384;
        ISSUE_K(j0, b0);
        ISSUE_VT(j0, b0 + 8192);
    }
    for (int j = j0; j < j1; ++j) {
        __syncthreads();   // drains tile-j loads; protects buffers from prior compute
        if (j + 1 < j1) {
            char* nb2 = lds + ((j + 1) & 1) * 16384;
            ISSUE_K(j + 1, nb2);
            ISSUE_VT(j + 1, nb2 + 8192);
        }
        if (j <= jmax) {
            char* Ks = lds + (j & 1) * 16384;
            char* Vt = Ks + 8192;
            const bool two = (qw0 >= j * 64 + 32);   // wave-uniform
            f32x16 sf0, sf1;
#pragma unroll
            for (int i = 0; i < 16; ++i) sf0[i] = 0.f;
            __builtin_amdgcn_s_setprio(1);
#pragma unroll
            for (int t = 0; t < 4; ++t) {
                const bf16x8 ak = *(const bf16x8*)(Ks + l31 * 128 + ((t * 32 + hi * 16) ^ ((l31 & 7) << 4)));
                sf0 = mfma32(ak, aqf[t], sf0);
            }
            __builtin_amdgcn_s_setprio(0);
            float tm;
            if (two) {
#pragma unroll
                for (int i = 0; i < 16; ++i) sf1[i] = 0.f;
                __builtin_amdgcn_s_setprio(1);
#pragma unroll
                for (int t = 0; t < 4; ++t) {
                    const int row = 32 + l31;
                    const bf16x8 ak = *(const bf16x8*)(Ks + row * 128 + ((t * 32 + hi * 16) ^ ((row & 7) << 4)));
                    sf1 = mfma32(ak, aqf[t], sf1);
                }
                __builtin_amdgcn_s_setprio(0);
                if (qw0 == j * 64 + 32) {
#pragma unroll
                    for (int rg = 0; rg < 16; ++rg) {
                        const int ss = j * 64 + 32 + (rg & 3) + 8 * (rg >> 2) + 4 * hi;
                        if (ss > qg) sf1[rg] = -3.0e38f;
                    }
                }
                tm = fmaxf(max16(sf0), max16(sf1));
            } else {
#pragma unroll
                for (int rg = 0; rg < 16; ++rg) {
                    const int ss = j * 64 + (rg & 3) + 8 * (rg >> 2) + 4 * hi;
                    if (ss > qg) sf0[rg] = -3.0e38f;
                }
                tm = max16(sf0);
            }
            tm = fmaxf(tm, __shfl_xor(tm, 32, 64));
            const float tmL = tm * CLOG;
            if (!__all(tmL <= mrun + 9.0f)) {           // rare path (and splitB cold start)
                const float mnew = fmaxf(mrun, tmL);
                const float corr = exp2f(mrun - mnew);
                mrun = mnew;
                lrun *= corr;
#pragma unroll
                for (int rq = 0; rq < 4; ++rq)
#pragma unroll
                    for (int rr = 0; rr < 4; ++rr) {
                        const int q = rr + 8 * rq + 4 * hi;
                        const float cb = __shfl(corr, q | (l & 32), 64);
                        oacc[0][rq * 4 + rr] *= cb;
                        oacc[1][rq * 4 + rr] *= cb;
                    }
            }
            uint32_t wv[8];
            SOFTMAX_PACK(sf0, wv)
            PVSTEP(wv, 0, 0)
            PVSTEP(wv, 1, 1)
            if (two) {
                SOFTMAX_PACK(sf1, wv)
                PVSTEP(wv, 0, 2)
                PVSTEP(wv, 1, 3)
            }
        }
    }
    // ---- epilogue: cross-half lrun, normalize by OWN l
    const float lfull = lrun + __shfl_xor(lrun, 32, 64);
    const float inv = rcpf(lfull);
    if (kind == 0) {
        // direct write (B,T,C) bf16 -- unchanged r6/r7 path
        const int b = bh >> 4, h = bh & 15;
#pragma unroll
        for (int rq = 0; rq < 4; ++rq)
#pragma unroll
            for (int rr = 0; rr < 4; ++rr) {
                const int q = rr + 8 * rq + 4 * hi;
                const float iv = __shfl(inv, q | (l & 32), 64);
                const int t = qw0 + q;
#pragma unroll
                for (int nb = 0; nb < 2; ++nb) {
                    const int c = h * 64 + nb * 32 + l31;
                    attb[((size_t)(b * 2048 + t)) * 1024 + c] = f2bf(oacc[nb][rq * 4 + rr] * iv);
                }
            }
    } else {
        // partial write: O/l bf16 [p][row 0..127][d 0..63], ml fp32 [p][row]
        const int p = ((bh << 3) + (s - 8)) * 2 + (kind - 1);
        u16* po = pO + (size_t)p * 8192;
#pragma unroll
        for (int rq = 0; rq < 4; ++rq)
#pragma unroll
            for (int rr = 0; rr < 4; ++rr) {
                const int q = rr + 8 * rq + 4 * hi;
                const float iv = __shfl(inv, q | (l & 32), 64);
                const int row = w * 32 + q;
#pragma unroll
                for (int nb = 0; nb < 2; ++nb)
                    po[row * 64 + nb * 32 + l31] = f2bf(oacc[nb][rq * 4 + rr] * iv);
            }
        if (hi == 0) {
            float2 v; v.x = mrun; v.y = lfull;
            pml[p * 128 + w * 32 + l31] = v;
        }
    }
}

// ---------------------------------------------------------------- split-KV merge
// One block per (bh, split strip s in 8..15): combine partial pair into attb.
// O = (wA*OA + wB*OB)/(wA+wB), w_i = l_i * 2^(m_i - max(mA,mB))   [exp2 domain]
__global__ __launch_bounds__(256) void attn_merge(const u16* __restrict__ pO,
                                                  const float2* __restrict__ pml,
                                                  u16* __restrict__ attb) {
    const int k = blockIdx.x;                  // 512 = 64 bh x 8 strips
    const int bh = k >> 3, s = 8 + (k & 7);
    const int tid = threadIdx.x;
    const int r = tid >> 1, dh = (tid & 1) << 5;
    const int pA = k * 2;
    const float2 a = pml[pA * 128 + r];
    const float2 bm = pml[pA * 128 + 128 + r];
    const float m = fmaxf(a.x, bm.x);
    const float wA = a.y * exp2f(a.x - m);
    const float wB = bm.y * exp2f(bm.x - m);
    const float inv = rcpf(wA + wB);
    const float sA = wA * inv, sB = wB * inv;
    const u16* oA = pO + (size_t)pA * 8192 + r * 64 + dh;
    const u16* oB = oA + 8192;
    const int b = bh >> 4, h = bh & 15;
    u16* dst = attb + ((size_t)(b * 2048 + s * 128 + r)) * 1024 + h * 64 + dh;
#pragma unroll
    for (int c = 0; c < 4; ++c) {
        const short8 va = *(const short8*)(oA + c * 8);
        const short8 vb = *(const short8*)(oB + c * 8);
        uint32_t packed[4];
#pragma unroll
        for (int i = 0; i < 4; ++i) {
            const float f0 = sA * bf2f((u16)va[2 * i])     + sB * bf2f((u16)vb[2 * i]);
            const float f1 = sA * bf2f((u16)va[2 * i + 1]) + sB * bf2f((u16)vb[2 * i + 1]);
            packed[i] = (uint32_t)f2bf(f0) | ((uint32_t)f2bf(f1) << 16);
        }
        uint4 o; o.x = packed[0]; o.y = packed[1]; o.z = packed[2]; o.w = packed[3];
        *(uint4*)(dst + c * 8) = o;
    }
}

// ---------------------------------------------------------------- output projection (fp32 out)
__global__ __launch_bounds__(256) void proj_gemm(const u16* __restrict__ attb, const u16* __restrict__ wpb,
                                                 const float* __restrict__ bp, float* __restrict__ out) {
    __shared__ char lds[32768];
    f32x4 acc[4][4] = {};
    const int id = blockIdx.x;
    const int xcd = id & 7, sl = id >> 3;
    const int nIdx = sl >> 3, mloc = sl & 7;
    const int m0 = (xcd * 8 + mloc) * 128;
    const int n0 = nIdx * 128;
    gemm_core<1024>(attb, wpb, m0, n0, lds, acc);
    const int tid = threadIdx.x;
    const int w = tid >> 6, l = tid & 63;
    const int lg = l >> 4, lc = l & 15;
    const int wm = (w >> 1) * 64, wn = (w & 1) * 64;
#pragma unroll
    for (int mi = 0; mi < 4; ++mi)
#pragma unroll
        for (int ni = 0; ni < 4; ++ni)
#pragma unroll
            for (int r = 0; r < 4; ++r) {
                const int m = m0 + wm + mi * 16 + lg * 4 + r;
                const int n = n0 + wn + ni * 16 + lc;
                out[(size_t)m * 1024 + n] = acc[mi][ni][r] + bp[n];
            }
}

// ---------------------------------------------------------------- launch
extern "C" void kernel_launch(void* const* d_in, const int* in_sizes, int n_in,
                              void* d_out, int out_size, void* d_ws, size_t ws_size,
                              hipStream_t stream) {
    const float* x  = (const float*)d_in[0];
    const float* Wk = (const float*)d_in[1];
    const float* bk = (const float*)d_in[2];
    const float* Wq = (const float*)d_in[3];
    const float* bq = (const float*)d_in[4];
    const float* Wv = (const float*)d_in[5];
    const float* bv = (const float*)d_in[6];
    const float* Wp = (const float*)d_in[7];
    const float* bp = (const float*)d_in[8];
    char* ws = (char*)d_ws;
    u16* xb   = (u16*)(ws);
    u16* wqkv = (u16*)(ws + 16777216);
    u16* wpb  = (u16*)(ws + 23068672);
    u16* qbuf = (u16*)(ws + 25165824);
    u16* kbuf = (u16*)(ws + 41943040);
    u16* vtb  = (u16*)(ws + 58720256);   // (B,H,D,T) pre-transposed V
    u16* attb = (u16*)(ws + 75497472);
    // partials overlay the xb/wqkv regions (dead after qkv_gemm):
    u16* pO     = (u16*)(ws);            // 1024 x 8192 u16 = 16 MB (== xb size)
    float2* pml = (float2*)(ws + 16777216);  // 1024 x 128 float2 = 1 MB (< wqkv size)

    cast_all<<<12288, 256, 0, stream>>>(x, Wq, Wk, Wv, Wp, xb, wqkv, wpb);
    qkv_gemm<<<1536, 256, 0, stream>>>(xb, wqkv, bq, bk, bv, qbuf, kbuf, vtb);
    attn_kernel<<<1536, 256, 0, stream>>>(qbuf, kbuf, vtb, attb, pO, pml);
    attn_merge<<<512, 256, 0, stream>>>(pO, pml, attb);
    proj_gemm<<<512, 256, 0, stream>>>(attb, wpb, bp, (float*)d_out);
}